// Round 6
// baseline (132.743 us; speedup 1.0000x reference)
//
#include <hip/hip_runtime.h>

#define NPTS  65536
#define NBC   76
#define NREP  8
#define KEYN  4864   // 76*64

typedef _Float16 f16;
typedef __fp16   h16x2 __attribute__((ext_vector_type(2)));   // cvt_pkrtz native type
typedef _Float16 f16x8 __attribute__((ext_vector_type(8)));
typedef float    f32x4 __attribute__((ext_vector_type(4)));

__device__ __forceinline__ float lrelu(float v) { return fmaxf(v, 0.01f * v); }

// two f32 -> packed f16 bits (RTZ; monotone, so max commutes with quantization)
__device__ __forceinline__ unsigned pkrtz(float lo, float hi) {
  h16x2 p = __builtin_amdgcn_cvt_pkrtz(lo, hi);
  return __builtin_bit_cast(unsigned, p);
}
// packed f16 bits -> packed order-preserving u16 keys (both halves).
// key 0 requires f16 NaN pattern => 0 doubles as "empty" sentinel.
__device__ __forceinline__ unsigned pkey(unsigned u) {
  unsigned t = (u >> 15) & 0x00010001u;
  return u ^ (0x80008000u | (t * 0x7FFFu));
}
__device__ __forceinline__ unsigned pkmax(unsigned a, unsigned b) {
  unsigned d;
  asm("v_pk_max_u16 %0, %1, %2" : "=v"(d) : "v"(a), "v"(b));
  return d;
}
// sign-extend bit b of x to all 32 bits (1 VALU op via v_bfe_i32)
__device__ __forceinline__ unsigned sext1(unsigned x, int b) {
  return (unsigned)(((int)(x << (31 - b))) >> 31);
}

// ---------------- kA: MLP (f16 MFMA) -> packed u16 keys to gmem ----------------
// kbuf layout: [tile 0..1023][row=ch_pair 0..31][pt 0..63] u32; row r = ch (2r, 2r+1)
__global__ __launch_bounds__(512, 8) void kA_mlp(
    const float* __restrict__ grid,
    const float* __restrict__ w1, const float* __restrict__ b1,
    const float* __restrict__ w2, const float* __restrict__ b2,
    const float* __restrict__ w3, const float* __restrict__ b3,
    unsigned* __restrict__ kbuf)
{
  // zA/zB [64pt][72k] f16, wf2/wf3 [64ch][72k] f16 = 36864 B -> 4 blocks/CU
  __shared__ __align__(16) unsigned char smem[36864];
  f16* zA  = (f16*)(smem);
  f16* zB  = (f16*)(smem + 9216);
  f16* wf2 = (f16*)(smem + 18432);
  f16* wf3 = (f16*)(smem + 27648);

  const int t    = threadIdx.x;
  const int lane = t & 63;
  const int wv   = t >> 6;          // 0..7
  const int n0   = blockIdx.x * 64;

  // grid loads early (longest-latency consumer is layer 1)
  float g0 = grid[n0 + lane], g1 = grid[NPTS + n0 + lane];

  // ---- stage w2/w3 as f16 rows [ch][k] (coalesced 32B/thread)
  {
    int ch = t >> 3, k0 = (t & 7) * 8;
    const float4* s2 = (const float4*)(w2 + ch * 64 + k0);
    float4 a = s2[0], b = s2[1];
    *(uint4*)&wf2[ch * 72 + k0] =
        make_uint4(pkrtz(a.x, a.y), pkrtz(a.z, a.w), pkrtz(b.x, b.y), pkrtz(b.z, b.w));
    const float4* s3 = (const float4*)(w3 + ch * 64 + k0);
    float4 c = s3[0], d = s3[1];
    *(uint4*)&wf3[ch * 72 + k0] =
        make_uint4(pkrtz(c.x, c.y), pkrtz(c.z, c.w), pkrtz(d.x, d.y), pkrtz(d.z, d.w));
  }

  // ---- layer 1: wave wv -> channels wv*8..wv*8+7, pt = lane. Writes zA[pt][k].
  {
    unsigned uo[4];
    #pragma unroll
    for (int p = 0; p < 4; ++p) {
      int j = wv * 8 + p * 2;
      float z0 = lrelu(w1[2 * j] * g0 + w1[2 * j + 1] * g1 + b1[j]);
      float z1 = lrelu(w1[2 * j + 2] * g0 + w1[2 * j + 3] * g1 + b1[j + 1]);
      uo[p] = pkrtz(z0, z1);
    }
    *(uint4*)&zA[lane * 72 + wv * 8] = make_uint4(uo[0], uo[1], uo[2], uo[3]);
  }
  __syncthreads();

  // ---- MFMA tiling: wave -> 16ch x 32pt; operands read as [row][k] (B^T form)
  const int chb = (wv & 3) * 16, pth = (wv >> 2) * 32;
  const int c15 = lane & 15, q = lane >> 4;
  const int chq = chb + q * 4;                 // 4 consecutive ch in C/D regs
  const int pt0 = pth + c15, pt1 = pth + 16 + c15;

  f32x4 acc0, acc1;

  // ---- layer 2 (A=wf2, B=zA) -> zB[pt][ch]
  {
    float4 bias = *(const float4*)(b2 + chq);
    acc0 = (f32x4){bias.x, bias.y, bias.z, bias.w};
    acc1 = acc0;
    #pragma unroll
    for (int k0 = 0; k0 < 64; k0 += 32) {
      f16x8 af = *(const f16x8*)&wf2[(chb + c15) * 72 + k0 + q * 8];
      f16x8 b0 = *(const f16x8*)&zA[pt0 * 72 + k0 + q * 8];
      f16x8 b1f = *(const f16x8*)&zA[pt1 * 72 + k0 + q * 8];
      acc0 = __builtin_amdgcn_mfma_f32_16x16x32_f16(af, b0, acc0, 0, 0, 0);
      acc1 = __builtin_amdgcn_mfma_f32_16x16x32_f16(af, b1f, acc1, 0, 0, 0);
    }
    // C/D: col=lane&15 (pt), row=q*4+reg (ch)
    *(uint2*)&zB[pt0 * 72 + chq] =
        make_uint2(pkrtz(lrelu(acc0[0]), lrelu(acc0[1])),
                   pkrtz(lrelu(acc0[2]), lrelu(acc0[3])));
    *(uint2*)&zB[pt1 * 72 + chq] =
        make_uint2(pkrtz(lrelu(acc1[0]), lrelu(acc1[1])),
                   pkrtz(lrelu(acc1[2]), lrelu(acc1[3])));
  }
  __syncthreads();

  // ---- layer 3 (A=wf3, B=zB) -> packed keys straight to gmem
  {
    float4 bias = *(const float4*)(b3 + chq);
    acc0 = (f32x4){bias.x, bias.y, bias.z, bias.w};
    acc1 = acc0;
    #pragma unroll
    for (int k0 = 0; k0 < 64; k0 += 32) {
      f16x8 af = *(const f16x8*)&wf3[(chb + c15) * 72 + k0 + q * 8];
      f16x8 b0 = *(const f16x8*)&zB[pt0 * 72 + k0 + q * 8];
      f16x8 b1f = *(const f16x8*)&zB[pt1 * 72 + k0 + q * 8];
      acc0 = __builtin_amdgcn_mfma_f32_16x16x32_f16(af, b0, acc0, 0, 0, 0);
      acc1 = __builtin_amdgcn_mfma_f32_16x16x32_f16(af, b1f, acc1, 0, 0, 0);
    }
    unsigned* kb = kbuf + (unsigned)blockIdx.x * 2048;
    int r0 = chq >> 1;   // row r holds ch (2r, 2r+1); chq even
    kb[r0 * 64 + pt0]       = pkey(pkrtz(lrelu(acc0[0]), lrelu(acc0[1])));
    kb[(r0 + 1) * 64 + pt0] = pkey(pkrtz(lrelu(acc0[2]), lrelu(acc0[3])));
    kb[r0 * 64 + pt1]       = pkey(pkrtz(lrelu(acc1[0]), lrelu(acc1[1])));
    kb[(r0 + 1) * 64 + pt1] = pkey(pkrtz(lrelu(acc1[2]), lrelu(acc1[3])));
  }
}

// ---------------- kB: masked max over keys -> 8-replica atomic fold ----------------
__global__ __launch_bounds__(512, 8) void kB_max(
    const int* __restrict__ x, const unsigned* __restrict__ kbuf,
    unsigned* __restrict__ keys)
{
  __shared__ unsigned zk[32 * 68];             // [ch_pair][pt], pad 68
  __shared__ unsigned long long mbits[NBC];

  const int t    = threadIdx.x;
  const int lane = t & 63;
  const int wv   = t >> 6;
  const int n0   = blockIdx.x * 64;

  // key tile: 512 threads x 1 uint4 = 8 KB
  const uint4 kv = *(const uint4*)(kbuf + (unsigned)blockIdx.x * 2048 + t * 4);

  // x loads + ballots: wave wv -> bc = wv + 8i
  int xv[10];
  #pragma unroll
  for (int i = 0; i < 10; ++i) {
    int bc = wv + 8 * i;
    xv[i] = (bc < NBC) ? x[(bc << 16) + n0 + lane] : 0;
  }

  *(uint4*)&zk[(t >> 4) * 68 + (t & 15) * 4] = kv;

  #pragma unroll
  for (int i = 0; i < 10; ++i) {
    int bc = wv + 8 * i;
    unsigned long long m = __ballot(xv[i] == 1);
    if (bc < NBC && lane == 0) mbits[bc] = m;
  }
  __syncthreads();   // the only barrier

  // thread -> row rw (ch pair) x 5 bc; 512 = 32 rows x 16 bc-groups
  const int rw = t & 31, bg = t >> 5;
  const int bc0 = bg * 5;

  unsigned mlo[5], mhi[5], uacc[5];
  #pragma unroll
  for (int ii = 0; ii < 5; ++ii) {
    int bc = bc0 + ii;
    unsigned long long m = (bc < NBC) ? mbits[bc] : 0ull;
    mlo[ii] = (unsigned)m;
    mhi[ii] = (unsigned)(m >> 32);
    uacc[ii] = 0u;
  }

  #pragma unroll
  for (int np = 0; np < 16; ++np) {
    uint4 z4 = *(const uint4*)&zk[rw * 68 + np * 4];
    const int p = np * 4, pb = p & 31;
    #pragma unroll
    for (int ii = 0; ii < 5; ++ii) {
      unsigned m = (p < 32) ? mlo[ii] : mhi[ii];
      unsigned s0 = sext1(m, pb),     s1 = sext1(m, pb + 1);
      unsigned s2 = sext1(m, pb + 2), s3 = sext1(m, pb + 3);
      unsigned a = uacc[ii];
      a = pkmax(a, z4.x & s0); a = pkmax(a, z4.y & s1);
      a = pkmax(a, z4.z & s2); a = pkmax(a, z4.w & s3);
      uacc[ii] = a;
    }
  }

  unsigned* krep = keys + (blockIdx.x & (NREP - 1)) * KEYN;
  #pragma unroll
  for (int ii = 0; ii < 5; ++ii) {
    int bc = bc0 + ii;
    if (bc < NBC) {
      unsigned lo = uacc[ii] & 0xFFFFu, hi = uacc[ii] >> 16;
      if (lo) atomicMax(&krep[bc * 64 + 2 * rw], lo);
      if (hi) atomicMax(&krep[bc * 64 + 2 * rw + 1], hi);
    }
  }
}

__global__ __launch_bounds__(256) void k2_fc(
    const unsigned* __restrict__ keys,
    const float* __restrict__ b1, const float* __restrict__ w2,
    const float* __restrict__ b2, const float* __restrict__ w3,
    const float* __restrict__ b3,
    const float* __restrict__ fcw, const float* __restrict__ fcb,
    float* __restrict__ out)
{
  __shared__ float flat[4864];
  __shared__ float za[64], zb[64], zf[64];
  const int t = threadIdx.x;

  // zero_feat = fp32 MLP(0,0): tiny, recomputed per block
  if (t < 64) za[t] = lrelu(b1[t]);
  __syncthreads();
  if (t < 64) {
    float s = b2[t];
    #pragma unroll 8
    for (int k = 0; k < 64; ++k) s += w2[t * 64 + k] * za[k];
    zb[t] = lrelu(s);
  }
  __syncthreads();
  if (t < 64) {
    float s = b3[t];
    #pragma unroll 8
    for (int k = 0; k < 64; ++k) s += w3[t * 64 + k] * zb[k];
    zf[t] = lrelu(s);
  }
  __syncthreads();

  // fold 8 replicas + decode u16 key -> f16 -> f32 (key 0 => empty => zero_feat)
  for (int idx = t; idx < 4864; idx += 256) {
    unsigned m = keys[idx];
    #pragma unroll
    for (int r = 1; r < NREP; ++r) m = max(m, keys[r * KEYN + idx]);
    float v;
    if (m) {
      unsigned u = (m & 0x8000u) ? (m ^ 0x8000u) : (~m & 0xFFFFu);
      unsigned short us = (unsigned short)u;
      v = (float)__builtin_bit_cast(f16, us);
    } else {
      v = zf[idx & 63];
    }
    flat[idx] = v;
  }
  __syncthreads();

  const int wv = t >> 6, lane = t & 63;
  const int o = blockIdx.x * 4 + wv;          // 128 blocks x 4 waves = 512 outputs
  const float* wrow = fcw + o * 1216;
  float fa0 = 0.f, fa1 = 0.f, fa2 = 0.f, fa3 = 0.f;
  #pragma unroll
  for (int i = 0; i < 19; ++i) {
    int jj = i * 64 + lane;
    float wvv = wrow[jj];
    fa0 += wvv * flat[jj];
    fa1 += wvv * flat[1216 + jj];
    fa2 += wvv * flat[2432 + jj];
    fa3 += wvv * flat[3648 + jj];
  }
  #pragma unroll
  for (int off = 32; off > 0; off >>= 1) {
    fa0 += __shfl_xor(fa0, off);
    fa1 += __shfl_xor(fa1, off);
    fa2 += __shfl_xor(fa2, off);
    fa3 += __shfl_xor(fa3, off);
  }
  const float scale = 0.028676966733820225f;  // 1/sqrt(1216)
  float cb = fcb[o];
  if (lane < 18) {
    out[(0 * 18 + lane) * 512 + o] = fa0 * scale + cb;
    out[(1 * 18 + lane) * 512 + o] = fa1 * scale + cb;
    out[(2 * 18 + lane) * 512 + o] = fa2 * scale + cb;
    out[(3 * 18 + lane) * 512 + o] = fa3 * scale + cb;
  }
}

extern "C" void kernel_launch(void* const* d_in, const int* in_sizes, int n_in,
                              void* d_out, int out_size, void* d_ws, size_t ws_size,
                              hipStream_t stream)
{
  const int*   x    = (const int*)d_in[0];
  const float* grid = (const float*)d_in[1];
  const float* w1   = (const float*)d_in[2];
  const float* b1   = (const float*)d_in[3];
  const float* w2   = (const float*)d_in[4];
  const float* b2   = (const float*)d_in[5];
  const float* w3   = (const float*)d_in[6];
  const float* b3   = (const float*)d_in[7];
  const float* fcw  = (const float*)d_in[8];
  const float* fcb  = (const float*)d_in[9];
  float* out = (float*)d_out;

  unsigned* keys = (unsigned*)d_ws;                  // 8 x 4864 u32 max-keys
  unsigned* kbuf = (unsigned*)d_ws + 65536;          // 1024 x 2048 u32 key tiles (8 MB)

  (void)hipMemsetAsync(d_ws, 0, NREP * KEYN * sizeof(unsigned), stream);
  hipLaunchKernelGGL(kA_mlp, dim3(1024), dim3(512), 0, stream,
                     grid, w1, b1, w2, b2, w3, b3, kbuf);
  hipLaunchKernelGGL(kB_max, dim3(1024), dim3(512), 0, stream,
                     x, kbuf, keys);
  hipLaunchKernelGGL(k2_fc, dim3(128), dim3(256), 0, stream,
                     keys, b1, w2, b2, w3, b3, fcw, fcb, out);
}

// Round 7
// 126.687 us; speedup vs baseline: 1.0478x; 1.0478x over previous
//
#include <hip/hip_runtime.h>

#define NPTS  65536
#define NBC   76
#define NREP  8
#define KEYN  4864   // 76*64

typedef _Float16 f16;
typedef __fp16   h16x2 __attribute__((ext_vector_type(2)));   // cvt_pkrtz native type
typedef _Float16 f16x8 __attribute__((ext_vector_type(8)));
typedef float    f32x4 __attribute__((ext_vector_type(4)));

__device__ __forceinline__ float lrelu(float v) { return fmaxf(v, 0.01f * v); }

// two f32 -> packed f16 bits (RTZ; monotone, so max commutes with quantization)
__device__ __forceinline__ unsigned pkrtz(float lo, float hi) {
  h16x2 p = __builtin_amdgcn_cvt_pkrtz(lo, hi);
  return __builtin_bit_cast(unsigned, p);
}
// packed f16 bits -> packed order-preserving u16 keys (both halves).
// key 0 requires f16 NaN pattern => 0 doubles as "empty" sentinel.
__device__ __forceinline__ unsigned pkey(unsigned u) {
  unsigned t = (u >> 15) & 0x00010001u;
  return u ^ (0x80008000u | (t * 0x7FFFu));
}
__device__ __forceinline__ unsigned pkmax(unsigned a, unsigned b) {
  unsigned d;
  asm("v_pk_max_u16 %0, %1, %2" : "=v"(d) : "v"(a), "v"(b));
  return d;
}
// sign-extend bit b of x to all 32 bits (v_bfe_i32)
__device__ __forceinline__ unsigned sext1(unsigned x, int b) {
  return (unsigned)(((int)(x << (31 - b))) >> 31);
}

// one MFMA layer: acc = bias; acc += A(16ch x 64k) * B(16pt x 64k) for 2 pt-tiles
__device__ __forceinline__ void mfma_layer(
    const f16* __restrict__ A, const f16* __restrict__ B,
    const float* __restrict__ bias,
    int chb, int c15, int q, int pt0, int pt1,
    f32x4& acc0, f32x4& acc1)
{
  float4 bv = *(const float4*)(bias + chb + q * 4);
  acc0 = (f32x4){bv.x, bv.y, bv.z, bv.w};
  acc1 = acc0;
  #pragma unroll
  for (int k0 = 0; k0 < 64; k0 += 32) {
    f16x8 af = *(const f16x8*)&A[(chb + c15) * 72 + k0 + q * 8];
    f16x8 b0 = *(const f16x8*)&B[pt0 * 72 + k0 + q * 8];
    f16x8 b1 = *(const f16x8*)&B[pt1 * 72 + k0 + q * 8];
    acc0 = __builtin_amdgcn_mfma_f32_16x16x32_f16(af, b0, acc0, 0, 0, 0);
    acc1 = __builtin_amdgcn_mfma_f32_16x16x32_f16(af, b1, acc1, 0, 0, 0);
  }
}

// pointwise layer 1: wave wv -> channels wv*8..+7, pt = lane; writes zA[pt][k]
__device__ __forceinline__ void layer1(
    f16* __restrict__ zA, const float* __restrict__ w1,
    const float* __restrict__ b1, int wv, int lane, float g0, float g1)
{
  unsigned uo[4];
  #pragma unroll
  for (int p = 0; p < 4; ++p) {
    int j = wv * 8 + p * 2;
    float z0 = lrelu(w1[2 * j] * g0 + w1[2 * j + 1] * g1 + b1[j]);
    float z1 = lrelu(w1[2 * j + 2] * g0 + w1[2 * j + 3] * g1 + b1[j + 1]);
    uo[p] = pkrtz(z0, z1);
  }
  *(uint4*)&zA[lane * 72 + wv * 8] = make_uint4(uo[0], uo[1], uo[2], uo[3]);
}

// ---------------- kA: MLP (f16 MFMA), T=2 tiles/block -> packed keys to gmem ----
// kbuf layout: [tile][row=ch_pair 0..31][pt 0..63] u32; row r = ch (2r, 2r+1)
__global__ __launch_bounds__(512, 4) void kA_mlp(
    const float* __restrict__ grid,
    const float* __restrict__ w1, const float* __restrict__ b1,
    const float* __restrict__ w2, const float* __restrict__ b2,
    const float* __restrict__ w3, const float* __restrict__ b3,
    unsigned* __restrict__ kbuf)
{
  // zA0/zA1/zB0/zB1 [64pt][72k] f16 + wf2/wf3 [64ch][72k] f16 = 55296 B -> 2 blk/CU
  __shared__ __align__(16) unsigned char smem[55296];
  f16* zA0 = (f16*)(smem);
  f16* zA1 = (f16*)(smem + 9216);
  f16* zB0 = (f16*)(smem + 18432);
  f16* zB1 = (f16*)(smem + 27648);
  f16* wf2 = (f16*)(smem + 36864);
  f16* wf3 = (f16*)(smem + 46080);

  const int t = threadIdx.x, lane = t & 63, wv = t >> 6;
  const int n0 = blockIdx.x * 128;

  // grid loads for both tiles up front
  float g0a = grid[n0 + lane],      g1a = grid[NPTS + n0 + lane];
  float g0b = grid[n0 + 64 + lane], g1b = grid[NPTS + n0 + 64 + lane];

  // stage w2/w3 as f16 rows [ch][k] (coalesced 32B/thread), once per block
  {
    int ch = t >> 3, k0 = (t & 7) * 8;
    const float4* s2 = (const float4*)(w2 + ch * 64 + k0);
    float4 a = s2[0], b = s2[1];
    *(uint4*)&wf2[ch * 72 + k0] =
        make_uint4(pkrtz(a.x, a.y), pkrtz(a.z, a.w), pkrtz(b.x, b.y), pkrtz(b.z, b.w));
    const float4* s3 = (const float4*)(w3 + ch * 64 + k0);
    float4 c = s3[0], d = s3[1];
    *(uint4*)&wf3[ch * 72 + k0] =
        make_uint4(pkrtz(c.x, c.y), pkrtz(c.z, c.w), pkrtz(d.x, d.y), pkrtz(d.z, d.w));
  }
  layer1(zA0, w1, b1, wv, lane, g0a, g1a);
  __syncthreads();                     // wf2/wf3 + zA0 ready

  const int chb = (wv & 3) * 16, pth = (wv >> 2) * 32;
  const int c15 = lane & 15, q = lane >> 4;
  const int chq = chb + q * 4;
  const int pt0 = pth + c15, pt1 = pth + 16 + c15;
  const int r0 = chq >> 1;

  // layer2 t0 -> zB0; layer1 t1 -> zA1 (independent work around the barrier)
  {
    f32x4 a0, a1;
    mfma_layer(wf2, zA0, b2, chb, c15, q, pt0, pt1, a0, a1);
    *(uint2*)&zB0[pt0 * 72 + chq] =
        make_uint2(pkrtz(lrelu(a0[0]), lrelu(a0[1])), pkrtz(lrelu(a0[2]), lrelu(a0[3])));
    *(uint2*)&zB0[pt1 * 72 + chq] =
        make_uint2(pkrtz(lrelu(a1[0]), lrelu(a1[1])), pkrtz(lrelu(a1[2]), lrelu(a1[3])));
  }
  layer1(zA1, w1, b1, wv, lane, g0b, g1b);
  __syncthreads();                     // zB0 + zA1 ready

  // layer3 t0 -> kbuf; layer2 t1 -> zB1
  {
    f32x4 c0, c1;
    mfma_layer(wf3, zB0, b3, chb, c15, q, pt0, pt1, c0, c1);
    unsigned* kb = kbuf + (unsigned)(blockIdx.x * 2) * 2048;
    kb[r0 * 64 + pt0]       = pkey(pkrtz(lrelu(c0[0]), lrelu(c0[1])));
    kb[(r0 + 1) * 64 + pt0] = pkey(pkrtz(lrelu(c0[2]), lrelu(c0[3])));
    kb[r0 * 64 + pt1]       = pkey(pkrtz(lrelu(c1[0]), lrelu(c1[1])));
    kb[(r0 + 1) * 64 + pt1] = pkey(pkrtz(lrelu(c1[2]), lrelu(c1[3])));
  }
  {
    f32x4 a0, a1;
    mfma_layer(wf2, zA1, b2, chb, c15, q, pt0, pt1, a0, a1);
    *(uint2*)&zB1[pt0 * 72 + chq] =
        make_uint2(pkrtz(lrelu(a0[0]), lrelu(a0[1])), pkrtz(lrelu(a0[2]), lrelu(a0[3])));
    *(uint2*)&zB1[pt1 * 72 + chq] =
        make_uint2(pkrtz(lrelu(a1[0]), lrelu(a1[1])), pkrtz(lrelu(a1[2]), lrelu(a1[3])));
  }
  __syncthreads();                     // zB1 ready

  // layer3 t1 -> kbuf
  {
    f32x4 c0, c1;
    mfma_layer(wf3, zB1, b3, chb, c15, q, pt0, pt1, c0, c1);
    unsigned* kb = kbuf + (unsigned)(blockIdx.x * 2 + 1) * 2048;
    kb[r0 * 64 + pt0]       = pkey(pkrtz(lrelu(c0[0]), lrelu(c0[1])));
    kb[(r0 + 1) * 64 + pt0] = pkey(pkrtz(lrelu(c0[2]), lrelu(c0[3])));
    kb[r0 * 64 + pt1]       = pkey(pkrtz(lrelu(c1[0]), lrelu(c1[1])));
    kb[(r0 + 1) * 64 + pt1] = pkey(pkrtz(lrelu(c1[2]), lrelu(c1[3])));
  }
}

// phase-B inner: masked max of one 64-pt tile into uacc[5]
__device__ __forceinline__ void phaseB(
    const unsigned* __restrict__ zk, const unsigned* mlo, const unsigned* mhi,
    unsigned* uacc, int rw)
{
  #pragma unroll
  for (int np = 0; np < 16; ++np) {
    uint4 z4 = *(const uint4*)&zk[rw * 68 + np * 4];
    const int p = np * 4, pb = p & 31;
    #pragma unroll
    for (int ii = 0; ii < 5; ++ii) {
      unsigned m = (p < 32) ? mlo[ii] : mhi[ii];
      unsigned s0 = sext1(m, pb),     s1 = sext1(m, pb + 1);
      unsigned s2 = sext1(m, pb + 2), s3 = sext1(m, pb + 3);
      unsigned a = uacc[ii];
      a = pkmax(a, z4.x & s0); a = pkmax(a, z4.y & s1);
      a = pkmax(a, z4.z & s2); a = pkmax(a, z4.w & s3);
      uacc[ii] = a;
    }
  }
}

// ---------------- kB: masked max, T=2 tiles/block -> 8-replica atomic fold ------
__global__ __launch_bounds__(512, 8) void kB_max(
    const int* __restrict__ x, const unsigned* __restrict__ kbuf,
    unsigned* __restrict__ keys)
{
  __shared__ unsigned zk0[32 * 68], zk1[32 * 68];
  __shared__ unsigned long long mb0[NBC], mb1[NBC];

  const int t = threadIdx.x, lane = t & 63, wv = t >> 6;
  const int n0 = blockIdx.x * 128;

  // key tiles for both halves (coalesced uint4)
  uint4 kv0 = *(const uint4*)(kbuf + (unsigned)(blockIdx.x * 2) * 2048 + t * 4);
  uint4 kv1 = *(const uint4*)(kbuf + (unsigned)(blockIdx.x * 2 + 1) * 2048 + t * 4);

  *(uint4*)&zk0[(t >> 4) * 68 + (t & 15) * 4] = kv0;

  // masks tile0 (xa regs reused for tile1 to cap VGPR)
  {
    int xa[10];
    #pragma unroll
    for (int i = 0; i < 10; ++i) {
      int bc = wv + 8 * i;
      if (bc < NBC) xa[i] = x[(bc << 16) + n0 + lane];
    }
    #pragma unroll
    for (int i = 0; i < 10; ++i) {
      int bc = wv + 8 * i;
      if (bc < NBC) {
        unsigned long long m = __ballot(xa[i] == 1);
        if (lane == 0) mb0[bc] = m;
      }
    }
    #pragma unroll
    for (int i = 0; i < 10; ++i) {
      int bc = wv + 8 * i;
      if (bc < NBC) xa[i] = x[(bc << 16) + n0 + 64 + lane];
    }
    #pragma unroll
    for (int i = 0; i < 10; ++i) {
      int bc = wv + 8 * i;
      if (bc < NBC) {
        unsigned long long m = __ballot(xa[i] == 1);
        if (lane == 0) mb1[bc] = m;
      }
    }
  }
  __syncthreads();                     // zk0 + masks ready
  *(uint4*)&zk1[(t >> 4) * 68 + (t & 15) * 4] = kv1;

  const int rw = t & 31, bg = t >> 5;
  const int bc0 = bg * 5;

  unsigned uacc[5] = {0u, 0u, 0u, 0u, 0u};
  unsigned mlo[5], mhi[5];

  #pragma unroll
  for (int ii = 0; ii < 5; ++ii) {
    int bc = bc0 + ii;
    unsigned long long m = (bc < NBC) ? mb0[bc] : 0ull;
    mlo[ii] = (unsigned)m; mhi[ii] = (unsigned)(m >> 32);
  }
  phaseB(zk0, mlo, mhi, uacc, rw);
  __syncthreads();                     // zk1 ready
  #pragma unroll
  for (int ii = 0; ii < 5; ++ii) {
    int bc = bc0 + ii;
    unsigned long long m = (bc < NBC) ? mb1[bc] : 0ull;
    mlo[ii] = (unsigned)m; mhi[ii] = (unsigned)(m >> 32);
  }
  phaseB(zk1, mlo, mhi, uacc, rw);

  unsigned* krep = keys + (blockIdx.x & (NREP - 1)) * KEYN;
  #pragma unroll
  for (int ii = 0; ii < 5; ++ii) {
    int bc = bc0 + ii;
    if (bc < NBC) {
      unsigned lo = uacc[ii] & 0xFFFFu, hi = uacc[ii] >> 16;
      if (lo) atomicMax(&krep[bc * 64 + 2 * rw], lo);
      if (hi) atomicMax(&krep[bc * 64 + 2 * rw + 1], hi);
    }
  }
}

__global__ __launch_bounds__(256) void k2_fc(
    const unsigned* __restrict__ keys,
    const float* __restrict__ b1, const float* __restrict__ w2,
    const float* __restrict__ b2, const float* __restrict__ w3,
    const float* __restrict__ b3,
    const float* __restrict__ fcw, const float* __restrict__ fcb,
    float* __restrict__ out)
{
  __shared__ float flat[4864];
  __shared__ float za[64], zb[64], zf[64];
  const int t = threadIdx.x;

  // zero_feat = fp32 MLP(0,0): tiny, recomputed per block
  if (t < 64) za[t] = lrelu(b1[t]);
  __syncthreads();
  if (t < 64) {
    float s = b2[t];
    #pragma unroll 8
    for (int k = 0; k < 64; ++k) s += w2[t * 64 + k] * za[k];
    zb[t] = lrelu(s);
  }
  __syncthreads();
  if (t < 64) {
    float s = b3[t];
    #pragma unroll 8
    for (int k = 0; k < 64; ++k) s += w3[t * 64 + k] * zb[k];
    zf[t] = lrelu(s);
  }
  __syncthreads();

  // fold 8 replicas + decode u16 key -> f16 -> f32 (key 0 => empty => zero_feat)
  for (int idx = t; idx < 4864; idx += 256) {
    unsigned m = keys[idx];
    #pragma unroll
    for (int r = 1; r < NREP; ++r) m = max(m, keys[r * KEYN + idx]);
    float v;
    if (m) {
      unsigned u = (m & 0x8000u) ? (m ^ 0x8000u) : (~m & 0xFFFFu);
      unsigned short us = (unsigned short)u;
      v = (float)__builtin_bit_cast(f16, us);
    } else {
      v = zf[idx & 63];
    }
    flat[idx] = v;
  }
  __syncthreads();

  const int wv = t >> 6, lane = t & 63;
  const int o = blockIdx.x * 4 + wv;          // 128 blocks x 4 waves = 512 outputs
  const float* wrow = fcw + o * 1216;
  float fa0 = 0.f, fa1 = 0.f, fa2 = 0.f, fa3 = 0.f;
  #pragma unroll
  for (int i = 0; i < 19; ++i) {
    int jj = i * 64 + lane;
    float wvv = wrow[jj];
    fa0 += wvv * flat[jj];
    fa1 += wvv * flat[1216 + jj];
    fa2 += wvv * flat[2432 + jj];
    fa3 += wvv * flat[3648 + jj];
  }
  #pragma unroll
  for (int off = 32; off > 0; off >>= 1) {
    fa0 += __shfl_xor(fa0, off);
    fa1 += __shfl_xor(fa1, off);
    fa2 += __shfl_xor(fa2, off);
    fa3 += __shfl_xor(fa3, off);
  }
  const float scale = 0.028676966733820225f;  // 1/sqrt(1216)
  float cb = fcb[o];
  if (lane < 18) {
    out[(0 * 18 + lane) * 512 + o] = fa0 * scale + cb;
    out[(1 * 18 + lane) * 512 + o] = fa1 * scale + cb;
    out[(2 * 18 + lane) * 512 + o] = fa2 * scale + cb;
    out[(3 * 18 + lane) * 512 + o] = fa3 * scale + cb;
  }
}

extern "C" void kernel_launch(void* const* d_in, const int* in_sizes, int n_in,
                              void* d_out, int out_size, void* d_ws, size_t ws_size,
                              hipStream_t stream)
{
  const int*   x    = (const int*)d_in[0];
  const float* grid = (const float*)d_in[1];
  const float* w1   = (const float*)d_in[2];
  const float* b1   = (const float*)d_in[3];
  const float* w2   = (const float*)d_in[4];
  const float* b2   = (const float*)d_in[5];
  const float* w3   = (const float*)d_in[6];
  const float* b3   = (const float*)d_in[7];
  const float* fcw  = (const float*)d_in[8];
  const float* fcb  = (const float*)d_in[9];
  float* out = (float*)d_out;

  unsigned* keys = (unsigned*)d_ws;                  // 8 x 4864 u32 max-keys
  unsigned* kbuf = (unsigned*)d_ws + 65536;          // 1024 x 2048 u32 key tiles (8 MB)

  (void)hipMemsetAsync(d_ws, 0, NREP * KEYN * sizeof(unsigned), stream);
  hipLaunchKernelGGL(kA_mlp, dim3(512), dim3(512), 0, stream,
                     grid, w1, b1, w2, b2, w3, b3, kbuf);
  hipLaunchKernelGGL(kB_max, dim3(512), dim3(512), 0, stream,
                     x, kbuf, keys);
  hipLaunchKernelGGL(k2_fc, dim3(128), dim3(256), 0, stream,
                     keys, b1, w2, b2, w3, b3, fcw, fcb, out);
}

// Round 9
// 124.985 us; speedup vs baseline: 1.0621x; 1.0136x over previous
//
#include <hip/hip_runtime.h>

#define NPTS  65536
#define NBC   76
#define NREP  8
#define KEYN  4864   // 76*64

typedef _Float16 f16;
typedef __fp16   h16x2 __attribute__((ext_vector_type(2)));   // cvt_pkrtz native type
typedef _Float16 f16x8 __attribute__((ext_vector_type(8)));
typedef float    f32x4 __attribute__((ext_vector_type(4)));

__device__ __forceinline__ float lrelu(float v) { return fmaxf(v, 0.01f * v); }

__device__ __forceinline__ unsigned pkrtz(float lo, float hi) {
  h16x2 p = __builtin_amdgcn_cvt_pkrtz(lo, hi);
  return __builtin_bit_cast(unsigned, p);
}
// packed f16 bits -> packed order-preserving u16 keys. Key 0 == "empty".
__device__ __forceinline__ unsigned pkey(unsigned u) {
  unsigned t = (u >> 15) & 0x00010001u;
  return u ^ (0x80008000u | (t * 0x7FFFu));
}
__device__ __forceinline__ unsigned pkmax(unsigned a, unsigned b) {
  unsigned d;
  asm("v_pk_max_u16 %0, %1, %2" : "=v"(d) : "v"(a), "v"(b));
  return d;
}
__device__ __forceinline__ unsigned sext1(unsigned x, int b) {
  return (unsigned)(((int)(x << (31 - b))) >> 31);
}
// 8 contiguous f32 -> f16x8 fragment (register-resident MFMA A-operand)
__device__ __forceinline__ f16x8 ldcvt8(const float* p) {
  float4 a = *(const float4*)p, b = *(const float4*)(p + 4);
  uint4 u = make_uint4(pkrtz(a.x, a.y), pkrtz(a.z, a.w),
                       pkrtz(b.x, b.y), pkrtz(b.z, b.w));
  return __builtin_bit_cast(f16x8, u);
}

// MFMA layer with register A-frags: acc = bias; 2 k-steps x 2 pt-tiles
__device__ __forceinline__ void mfma_layer_r(
    const f16x8* wr, const f16* __restrict__ B, const float* __restrict__ bias,
    int chq, int q, int pt0, int pt1, f32x4& acc0, f32x4& acc1)
{
  float4 bv = *(const float4*)(bias + chq);
  acc0 = (f32x4){bv.x, bv.y, bv.z, bv.w};
  acc1 = acc0;
  #pragma unroll
  for (int s = 0; s < 2; ++s) {
    int k0 = s * 32;
    f16x8 b0 = *(const f16x8*)&B[pt0 * 72 + k0 + q * 8];
    f16x8 b1 = *(const f16x8*)&B[pt1 * 72 + k0 + q * 8];
    acc0 = __builtin_amdgcn_mfma_f32_16x16x32_f16(wr[s], b0, acc0, 0, 0, 0);
    acc1 = __builtin_amdgcn_mfma_f32_16x16x32_f16(wr[s], b1, acc1, 0, 0, 0);
  }
}

// pointwise layer 1: wave wv -> channels wv*8..+7, pt = lane; writes zA[pt][k]
__device__ __forceinline__ void layer1(
    f16* __restrict__ zA, const float* __restrict__ w1,
    const float* __restrict__ b1, int wv, int lane, float g0, float g1)
{
  unsigned uo[4];
  #pragma unroll
  for (int p = 0; p < 4; ++p) {
    int j = wv * 8 + p * 2;
    float z0 = lrelu(w1[2 * j] * g0 + w1[2 * j + 1] * g1 + b1[j]);
    float z1 = lrelu(w1[2 * j + 2] * g0 + w1[2 * j + 3] * g1 + b1[j + 1]);
    uo[p] = pkrtz(z0, z1);
  }
  *(uint4*)&zA[lane * 72 + wv * 8] = make_uint4(uo[0], uo[1], uo[2], uo[3]);
}

// ---------------- kA: MLP (f16 MFMA, reg weights), T=2 -> packed keys ----------
__global__ __launch_bounds__(512, 8) void kA_mlp(
    const float* __restrict__ grid,
    const float* __restrict__ w1, const float* __restrict__ b1,
    const float* __restrict__ w2, const float* __restrict__ b2,
    const float* __restrict__ w3, const float* __restrict__ b3,
    unsigned* __restrict__ kbuf, unsigned* __restrict__ keys)
{
  // zA0/zA1/zB0/zB1 [64pt][72k] f16 = 36864 B -> 4 blocks/CU, 8 waves/SIMD
  __shared__ __align__(16) unsigned char smem[36864];
  f16* zA0 = (f16*)(smem);
  f16* zA1 = (f16*)(smem + 9216);
  f16* zB0 = (f16*)(smem + 18432);
  f16* zB1 = (f16*)(smem + 27648);

  const int t = threadIdx.x, lane = t & 63, wv = t >> 6;
  const int n0 = blockIdx.x * 128;

  // zero the atomic key replicas (replaces a separate memset dispatch; kB runs
  // strictly after kA in stream order)
  if (blockIdx.x < 76) keys[blockIdx.x * 512 + t] = 0u;

  // grid loads for both tiles up front
  float g0a = grid[n0 + lane],      g1a = grid[NPTS + n0 + lane];
  float g0b = grid[n0 + 64 + lane], g1b = grid[NPTS + n0 + 64 + lane];

  const int chb = (wv & 3) * 16, pth = (wv >> 2) * 32;
  const int c15 = lane & 15, q = lane >> 4;
  const int chq = chb + q * 4;
  const int pt0 = pth + c15, pt1 = pth + 16 + c15;
  const int r0 = chq >> 1;

  // weight A-fragments straight to registers (off the barrier critical path)
  f16x8 wr2[2], wr3[2];
  {
    const int row = (chb + c15) * 64 + q * 8;
    wr2[0] = ldcvt8(w2 + row);  wr2[1] = ldcvt8(w2 + row + 32);
    wr3[0] = ldcvt8(w3 + row);  wr3[1] = ldcvt8(w3 + row + 32);
  }

  layer1(zA0, w1, b1, wv, lane, g0a, g1a);
  layer1(zA1, w1, b1, wv, lane, g0b, g1b);
  __syncthreads();                      // barrier 1: zA0 + zA1 ready

  f32x4 a0, a1;
  mfma_layer_r(wr2, zA0, b2, chq, q, pt0, pt1, a0, a1);
  *(uint2*)&zB0[pt0 * 72 + chq] =
      make_uint2(pkrtz(lrelu(a0[0]), lrelu(a0[1])), pkrtz(lrelu(a0[2]), lrelu(a0[3])));
  *(uint2*)&zB0[pt1 * 72 + chq] =
      make_uint2(pkrtz(lrelu(a1[0]), lrelu(a1[1])), pkrtz(lrelu(a1[2]), lrelu(a1[3])));
  mfma_layer_r(wr2, zA1, b2, chq, q, pt0, pt1, a0, a1);
  *(uint2*)&zB1[pt0 * 72 + chq] =
      make_uint2(pkrtz(lrelu(a0[0]), lrelu(a0[1])), pkrtz(lrelu(a0[2]), lrelu(a0[3])));
  *(uint2*)&zB1[pt1 * 72 + chq] =
      make_uint2(pkrtz(lrelu(a1[0]), lrelu(a1[1])), pkrtz(lrelu(a1[2]), lrelu(a1[3])));
  __syncthreads();                      // barrier 2: zB0 + zB1 ready

  mfma_layer_r(wr3, zB0, b3, chq, q, pt0, pt1, a0, a1);
  {
    unsigned* kb = kbuf + (unsigned)(blockIdx.x * 2) * 2048;
    kb[r0 * 64 + pt0]       = pkey(pkrtz(lrelu(a0[0]), lrelu(a0[1])));
    kb[(r0 + 1) * 64 + pt0] = pkey(pkrtz(lrelu(a0[2]), lrelu(a0[3])));
    kb[r0 * 64 + pt1]       = pkey(pkrtz(lrelu(a1[0]), lrelu(a1[1])));
    kb[(r0 + 1) * 64 + pt1] = pkey(pkrtz(lrelu(a1[2]), lrelu(a1[3])));
  }
  mfma_layer_r(wr3, zB1, b3, chq, q, pt0, pt1, a0, a1);
  {
    unsigned* kb = kbuf + (unsigned)(blockIdx.x * 2 + 1) * 2048;
    kb[r0 * 64 + pt0]       = pkey(pkrtz(lrelu(a0[0]), lrelu(a0[1])));
    kb[(r0 + 1) * 64 + pt0] = pkey(pkrtz(lrelu(a0[2]), lrelu(a0[3])));
    kb[r0 * 64 + pt1]       = pkey(pkrtz(lrelu(a1[0]), lrelu(a1[1])));
    kb[(r0 + 1) * 64 + pt1] = pkey(pkrtz(lrelu(a1[2]), lrelu(a1[3])));
  }
}

// phase-B inner: masked max of one 64-pt tile into uacc[5]
__device__ __forceinline__ void phaseB(
    const unsigned* __restrict__ zk, const unsigned* mlo, const unsigned* mhi,
    unsigned* uacc, int rw)
{
  #pragma unroll
  for (int np = 0; np < 16; ++np) {
    uint4 z4 = *(const uint4*)&zk[rw * 68 + np * 4];
    const int p = np * 4, pb = p & 31;
    #pragma unroll
    for (int ii = 0; ii < 5; ++ii) {
      unsigned m = (p < 32) ? mlo[ii] : mhi[ii];
      unsigned s0 = sext1(m, pb),     s1 = sext1(m, pb + 1);
      unsigned s2 = sext1(m, pb + 2), s3 = sext1(m, pb + 3);
      unsigned a = uacc[ii];
      a = pkmax(a, z4.x & s0); a = pkmax(a, z4.y & s1);
      a = pkmax(a, z4.z & s2); a = pkmax(a, z4.w & s3);
      uacc[ii] = a;
    }
  }
}

// ---------------- kB: masked max, T=2 tiles/block -> 8-replica atomic fold ------
__global__ __launch_bounds__(512, 8) void kB_max(
    const int* __restrict__ x, const unsigned* __restrict__ kbuf,
    unsigned* __restrict__ keys)
{
  __shared__ unsigned zk0[32 * 68], zk1[32 * 68];
  __shared__ unsigned long long mb0[NBC], mb1[NBC];

  const int t = threadIdx.x, lane = t & 63, wv = t >> 6;
  const int n0 = blockIdx.x * 128;

  uint4 kv0 = *(const uint4*)(kbuf + (unsigned)(blockIdx.x * 2) * 2048 + t * 4);
  uint4 kv1 = *(const uint4*)(kbuf + (unsigned)(blockIdx.x * 2 + 1) * 2048 + t * 4);
  *(uint4*)&zk0[(t >> 4) * 68 + (t & 15) * 4] = kv0;

  {
    int xa[10];
    #pragma unroll
    for (int i = 0; i < 10; ++i) {
      int bc = wv + 8 * i;
      if (bc < NBC) xa[i] = x[(bc << 16) + n0 + lane];
    }
    #pragma unroll
    for (int i = 0; i < 10; ++i) {
      int bc = wv + 8 * i;
      if (bc < NBC) {
        unsigned long long m = __ballot(xa[i] == 1);
        if (lane == 0) mb0[bc] = m;
      }
    }
    #pragma unroll
    for (int i = 0; i < 10; ++i) {
      int bc = wv + 8 * i;
      if (bc < NBC) xa[i] = x[(bc << 16) + n0 + 64 + lane];
    }
    #pragma unroll
    for (int i = 0; i < 10; ++i) {
      int bc = wv + 8 * i;
      if (bc < NBC) {
        unsigned long long m = __ballot(xa[i] == 1);
        if (lane == 0) mb1[bc] = m;
      }
    }
  }
  __syncthreads();                     // zk0 + masks ready
  *(uint4*)&zk1[(t >> 4) * 68 + (t & 15) * 4] = kv1;

  const int rw = t & 31, bg = t >> 5;
  const int bc0 = bg * 5;

  unsigned uacc[5] = {0u, 0u, 0u, 0u, 0u};
  unsigned mlo[5], mhi[5];
  #pragma unroll
  for (int ii = 0; ii < 5; ++ii) {
    int bc = bc0 + ii;
    unsigned long long m = (bc < NBC) ? mb0[bc] : 0ull;
    mlo[ii] = (unsigned)m; mhi[ii] = (unsigned)(m >> 32);
  }
  phaseB(zk0, mlo, mhi, uacc, rw);
  __syncthreads();                     // zk1 ready
  #pragma unroll
  for (int ii = 0; ii < 5; ++ii) {
    int bc = bc0 + ii;
    unsigned long long m = (bc < NBC) ? mb1[bc] : 0ull;
    mlo[ii] = (unsigned)m; mhi[ii] = (unsigned)(m >> 32);
  }
  phaseB(zk1, mlo, mhi, uacc, rw);

  unsigned* krep = keys + (blockIdx.x & (NREP - 1)) * KEYN;
  #pragma unroll
  for (int ii = 0; ii < 5; ++ii) {
    int bc = bc0 + ii;
    if (bc < NBC) {
      unsigned lo = uacc[ii] & 0xFFFFu, hi = uacc[ii] >> 16;
      if (lo) atomicMax(&krep[bc * 64 + 2 * rw], lo);
      if (hi) atomicMax(&krep[bc * 64 + 2 * rw + 1], hi);
    }
  }
}

__global__ __launch_bounds__(256) void k2_fc(
    const unsigned* __restrict__ keys,
    const float* __restrict__ b1, const float* __restrict__ w2,
    const float* __restrict__ b2, const float* __restrict__ w3,
    const float* __restrict__ b3,
    const float* __restrict__ fcw, const float* __restrict__ fcb,
    float* __restrict__ out)
{
  __shared__ float flat[4864];
  __shared__ float za[64], zb[64], zf[64];
  const int t = threadIdx.x;

  // zero_feat = fp32 MLP(0,0): tiny, recomputed per block
  if (t < 64) za[t] = lrelu(b1[t]);
  __syncthreads();
  if (t < 64) {
    float s = b2[t];
    #pragma unroll 8
    for (int k = 0; k < 64; ++k) s += w2[t * 64 + k] * za[k];
    zb[t] = lrelu(s);
  }
  __syncthreads();
  if (t < 64) {
    float s = b3[t];
    #pragma unroll 8
    for (int k = 0; k < 64; ++k) s += w3[t * 64 + k] * zb[k];
    zf[t] = lrelu(s);
  }
  __syncthreads();

  // fold 8 replicas + decode u16 key -> f16 -> f32 (key 0 => empty => zero_feat)
  for (int idx = t; idx < 4864; idx += 256) {
    unsigned m = keys[idx];
    #pragma unroll
    for (int r = 1; r < NREP; ++r) m = max(m, keys[r * KEYN + idx]);
    float v;
    if (m) {
      unsigned u = (m & 0x8000u) ? (m ^ 0x8000u) : (~m & 0xFFFFu);
      unsigned short us = (unsigned short)u;
      v = (float)__builtin_bit_cast(f16, us);
    } else {
      v = zf[idx & 63];
    }
    flat[idx] = v;
  }
  __syncthreads();

  const int wv = t >> 6, lane = t & 63;
  const int o = blockIdx.x * 4 + wv;          // 128 blocks x 4 waves = 512 outputs
  const float* wrow = fcw + o * 1216;
  float fa0 = 0.f, fa1 = 0.f, fa2 = 0.f, fa3 = 0.f;
  #pragma unroll
  for (int i = 0; i < 19; ++i) {
    int jj = i * 64 + lane;
    float wvv = wrow[jj];
    fa0 += wvv * flat[jj];
    fa1 += wvv * flat[1216 + jj];
    fa2 += wvv * flat[2432 + jj];
    fa3 += wvv * flat[3648 + jj];
  }
  #pragma unroll
  for (int off = 32; off > 0; off >>= 1) {
    fa0 += __shfl_xor(fa0, off);
    fa1 += __shfl_xor(fa1, off);
    fa2 += __shfl_xor(fa2, off);
    fa3 += __shfl_xor(fa3, off);
  }
  const float scale = 0.028676966733820225f;  // 1/sqrt(1216)
  float cb = fcb[o];
  if (lane < 18) {
    out[(0 * 18 + lane) * 512 + o] = fa0 * scale + cb;
    out[(1 * 18 + lane) * 512 + o] = fa1 * scale + cb;
    out[(2 * 18 + lane) * 512 + o] = fa2 * scale + cb;
    out[(3 * 18 + lane) * 512 + o] = fa3 * scale + cb;
  }
}

extern "C" void kernel_launch(void* const* d_in, const int* in_sizes, int n_in,
                              void* d_out, int out_size, void* d_ws, size_t ws_size,
                              hipStream_t stream)
{
  const int*   x    = (const int*)d_in[0];
  const float* grid = (const float*)d_in[1];
  const float* w1   = (const float*)d_in[2];
  const float* b1   = (const float*)d_in[3];
  const float* w2   = (const float*)d_in[4];
  const float* b2   = (const float*)d_in[5];
  const float* w3   = (const float*)d_in[6];
  const float* b3   = (const float*)d_in[7];
  const float* fcw  = (const float*)d_in[8];
  const float* fcb  = (const float*)d_in[9];
  float* out = (float*)d_out;

  unsigned* keys = (unsigned*)d_ws;                  // 8 x 4864 u32 max-keys
  unsigned* kbuf = (unsigned*)d_ws + 65536;          // 1024 x 2048 u32 key tiles

  hipLaunchKernelGGL(kA_mlp, dim3(512), dim3(512), 0, stream,
                     grid, w1, b1, w2, b2, w3, b3, kbuf, keys);
  hipLaunchKernelGGL(kB_max, dim3(512), dim3(512), 0, stream,
                     x, kbuf, keys);
  hipLaunchKernelGGL(k2_fc, dim3(128), dim3(256), 0, stream,
                     keys, b1, w2, b2, w3, b3, fcw, fcb, out);
}